// Round 11
// baseline (225.910 us; speedup 1.0000x reference)
//
#include <hip/hip_runtime.h>
#include <hip/hip_bf16.h>

// ---------------------------------------------------------------------------
// TwoLayerGCN. Round 27: spmm load-balance -- 4 nodes per wave.
// R26 matched (-6.2us, absmax bit-exact 0.75): gld16 gemm staging in.
// Remaining measurable inefficiency: spmm wave imbalance. 1 node/wave,
// Poisson(16) degrees -> block waits on max of 4 waves (~22 vs mean 16,
// +35%), consistent with 65-67% occupancy. Now each wave sums 4 nodes
// (64 +- 8) -> block overhead ~15%. Per-node loops/order/arithmetic
// untouched -> absmax must stay exactly 0.75. Grid (N+15)/16 = 3125.
// Predict spmm256 ~33->29us (occ 67->~75), spmm128 ~14->12.5,
// total 220.8 -> ~216us. If NULL: spmm fully at DRAM random-line floor
// (levers bytes/MLP/locality/fusion/quant all measured-exhausted).
// fp8 x/h1 (R17/R20) + binned build (R18/R19) + 16-deep MLP (R21/R23) +
// gld16 gemm staging (R26) retained.
// ---------------------------------------------------------------------------

typedef short v8s __attribute__((ext_vector_type(8)));
typedef float v4f __attribute__((ext_vector_type(4)));
typedef float v2f __attribute__((ext_vector_type(2)));

#define BKT_CAP 6144   // stage capacity per 256-node bucket (mean 4096, std 64)

__device__ inline unsigned bf16u(float f) {           // fp32 -> bf16 bits (RNE)
    unsigned u = __builtin_bit_cast(unsigned, f);
    return (u + 0x7fffu + ((u >> 16) & 1u)) >> 16;
}
__device__ inline float bflo(unsigned v) { return __builtin_bit_cast(float, v << 16); }
__device__ inline float bfhi(unsigned v) { return __builtin_bit_cast(float, v & 0xffff0000u); }

__device__ __forceinline__ void gld16(const void* gsrc, void* ldst) {
    __builtin_amdgcn_global_load_lds(
        (const __attribute__((address_space(1))) void*)gsrc,
        (__attribute__((address_space(3))) void*)ldst, 16, 0, 0);
}

// ------------- fused prep: x->fp8, W^T, bcnt zero (no memset) ---------------
__global__ __launch_bounds__(256) void prep(
    const float* __restrict__ x, unsigned char* __restrict__ x8,
    const float* __restrict__ W1, ushort* __restrict__ Wt1,
    const float* __restrict__ W2, ushort* __restrict__ Wt2,
    int* __restrict__ bcnt)
{
    int b = blockIdx.x;
    int t = threadIdx.x;
    if (b < 6250) {
        int i = b * 256 + t;                 // n4 = 1600000
        if (i < 1600000) {
            float4 v = ((const float4*)x)[i];
            int pk = __builtin_amdgcn_cvt_pk_fp8_f32(v.x, v.y, 0, false);
            pk = __builtin_amdgcn_cvt_pk_fp8_f32(v.z, v.w, pk, true);
            ((unsigned*)x8)[i] = (unsigned)pk;
        }
    } else if (b < 6506) {
        int n = b - 6250;
        if (t < 128) Wt1[n * 128 + t] = (ushort)bf16u(W1[t * 256 + n]);
    } else if (b < 6762) {
        int n = b - 6506;
        Wt2[n * 256 + t] = (ushort)bf16u(W2[t * 256 + n]);
    } else {
        bcnt[t] = 0;
    }
}

// --------------- pass A: bin edges by 256-node bucket (dst>>8) --------------
__global__ __launch_bounds__(256) void bin_pass(
    const int* __restrict__ src, const int* __restrict__ dst,
    const float* __restrict__ w, int* __restrict__ bcnt,
    uint2* __restrict__ stage, float* __restrict__ g, int E)
{
    __shared__ int hist[256];
    __shared__ int excl[256];
    __shared__ int gbase[256];
    __shared__ uint2 stg[2048];

    int t = threadIdx.x, b = blockIdx.x;
    if (b < 128) g[b * 256 + t] = 0.f;

    int e0 = b * 2048;
    hist[t] = 0;
    __syncthreads();

    int d_[8]; unsigned pk_[8]; int rk_[8]; int bk_[8];
    #pragma unroll
    for (int j = 0; j < 8; j++) {
        int e = e0 + t + j * 256;               // coalesced
        if (e < E) {
            int d = dst[e];
            d_[j] = d;
            bk_[j] = d >> 8;
            pk_[j] = (unsigned)src[e] | (bf16u(w[e]) << 16);
            rk_[j] = atomicAdd(&hist[bk_[j]], 1);
        } else d_[j] = -1;
    }
    __syncthreads();

    int cnt = hist[t];
    excl[t] = cnt;
    __syncthreads();
    for (int o = 1; o < 256; o <<= 1) {         // inclusive scan
        int v = (t >= o) ? excl[t - o] : 0;
        __syncthreads();
        excl[t] += v;
        __syncthreads();
    }
    int ex = excl[t] - cnt;                     // exclusive
    if (cnt > 0) gbase[t] = atomicAdd(&bcnt[t], cnt);   // reserve run
    __syncthreads();
    excl[t] = ex;
    __syncthreads();

    #pragma unroll
    for (int j = 0; j < 8; j++)
        if (d_[j] >= 0)
            stg[excl[bk_[j]] + rk_[j]] = make_uint2(pk_[j], (unsigned)d_[j]);
    __syncthreads();

    int nval = min(2048, E - e0);
    #pragma unroll
    for (int j = 0; j < 8; j++) {
        int sidx = t + j * 256;                 // consecutive lanes -> consecutive gpos
        if (sidx < nval) {
            uint2 ent = stg[sidx];
            int bk = (int)(ent.y >> 8);
            stage[(size_t)bk * BKT_CAP + gbase[bk] + sidx - excl[bk]] = ent;
        }
    }
}

// ------ pass B: per-bucket histogram + scan -> off[], sort -> edges[] -------
__global__ __launch_bounds__(256) void sort_build(
    const uint2* __restrict__ stage, const int* __restrict__ bcnt,
    unsigned* __restrict__ edges, int* __restrict__ off, int N, int E)
{
    __shared__ unsigned sorted[BKT_CAP];        // 24 KB
    __shared__ int hist[256];
    __shared__ int s[256];
    __shared__ int cur[256];
    __shared__ int psum[4];
    __shared__ int sbase;

    int t = threadIdx.x, b = blockIdx.x;
    const uint2* reg = stage + (size_t)b * BKT_CAP;
    int cnt = bcnt[b];

    // bucket base = sum of bcnt[0..b-1]
    int pred = (t < b) ? bcnt[t] : 0;
    #pragma unroll
    for (int o = 32; o > 0; o >>= 1) pred += __shfl_down(pred, o, 64);
    if ((t & 63) == 0) psum[t >> 6] = pred;
    hist[t] = 0;
    __syncthreads();
    if (t == 0) sbase = psum[0] + psum[1] + psum[2] + psum[3];

    for (int i = t; i < cnt; i += 256)
        atomicAdd(&hist[reg[i].y & 255u], 1);   // LDS atomic
    __syncthreads();

    int h = hist[t];
    s[t] = h;
    __syncthreads();
    for (int o = 1; o < 256; o <<= 1) {         // inclusive scan
        int v = (t >= o) ? s[t - o] : 0;
        __syncthreads();
        s[t] += v;
        __syncthreads();
    }
    int ex = s[t] - h;                          // exclusive
    cur[t] = ex;
    __syncthreads();

    int nn = b * 256 + t;
    if (nn <= N) off[nn] = sbase + ex;          // nn==N lands off[N]=E exactly

    for (int i = t; i < cnt; i += 256) {
        uint2 ent = reg[i];
        int r = atomicAdd(&cur[ent.y & 255u], 1);
        sorted[r] = ent.x;
    }
    __syncthreads();
    for (int i = t; i < cnt; i += 256)
        edges[sbase + i] = sorted[i];
}

// --------------- gather SpMM layer 1: fp8 e4m3 in, bf16 out -----------------
// 16-deep gather pipeline; 4 nodes per wave (load-balance smoothing).
__global__ __launch_bounds__(256) void spmm128(
    const unsigned char* __restrict__ x8, const int* __restrict__ off,
    const unsigned* __restrict__ edges, ushort* __restrict__ S, int n)
{
    int wave = threadIdx.x >> 6, lane = threadIdx.x & 63;
    int nbase = blockIdx.x * 16 + wave * 4;
    const ushort* base = (const ushort*)x8;   // row stride 64 ushorts (128B)
    for (int i = 0; i < 4; i++) {
        int node = nbase + i;
        if (node >= n) continue;              // wave-uniform
        int e0 = off[node], e1 = off[node + 1];
        float a0 = 0.f, a1 = 0.f;
        int e = e0;
        for (; e + 16 <= e1; e += 16) {
            unsigned ed[16]; ushort v[16];
            #pragma unroll
            for (int j = 0; j < 16; j++) ed[j] = edges[e + j];
            #pragma unroll
            for (int j = 0; j < 16; j++)
                v[j] = base[(size_t)(ed[j] & 0xffffu) * 64 + lane];
            #pragma unroll
            for (int j = 0; j < 16; j++) {
                float w = bfhi(ed[j]);
                v2f f = __builtin_amdgcn_cvt_pk_f32_fp8((int)v[j], false);
                a0 += f.x * w;
                a1 += f.y * w;
            }
        }
        for (; e + 4 <= e1; e += 4) {
            unsigned ed[4]; ushort v[4];
            #pragma unroll
            for (int j = 0; j < 4; j++) ed[j] = edges[e + j];
            #pragma unroll
            for (int j = 0; j < 4; j++)
                v[j] = base[(size_t)(ed[j] & 0xffffu) * 64 + lane];
            #pragma unroll
            for (int j = 0; j < 4; j++) {
                float w = bfhi(ed[j]);
                v2f f = __builtin_amdgcn_cvt_pk_f32_fp8((int)v[j], false);
                a0 += f.x * w;
                a1 += f.y * w;
            }
        }
        for (; e < e1; e++) {
            unsigned ed = edges[e];
            float w0 = bfhi(ed);
            ushort v0 = base[(size_t)(ed & 0xffffu) * 64 + lane];
            v2f f0 = __builtin_amdgcn_cvt_pk_f32_fp8((int)v0, false);
            a0 += f0.x * w0;
            a1 += f0.y * w0;
        }
        ((unsigned*)S)[(size_t)node * 64 + lane] = (bf16u(a1) << 16) | bf16u(a0);
    }
}

// --------------- gather SpMM layer 2: fp8 e4m3 in, bf16 out -----------------
// 16-deep gather pipeline; 4 nodes per wave (load-balance smoothing).
__global__ __launch_bounds__(256) void spmm256(
    const unsigned char* __restrict__ h8, const int* __restrict__ off,
    const unsigned* __restrict__ edges, ushort* __restrict__ S, int n)
{
    int wave = threadIdx.x >> 6, lane = threadIdx.x & 63;
    int nbase = blockIdx.x * 16 + wave * 4;
    const unsigned* base = (const unsigned*)h8;    // row stride 64 uints (256B)
    for (int i = 0; i < 4; i++) {
        int node = nbase + i;
        if (node >= n) continue;              // wave-uniform
        int e0 = off[node], e1 = off[node + 1];
        float a0 = 0.f, a1 = 0.f, a2 = 0.f, a3 = 0.f;
        int e = e0;
        for (; e + 16 <= e1; e += 16) {
            unsigned ed[16]; unsigned v[16];
            #pragma unroll
            for (int j = 0; j < 16; j++) ed[j] = edges[e + j];
            #pragma unroll
            for (int j = 0; j < 16; j++)
                v[j] = base[(size_t)(ed[j] & 0xffffu) * 64 + lane];
            #pragma unroll
            for (int j = 0; j < 16; j++) {
                float w = bfhi(ed[j]);
                v2f l = __builtin_amdgcn_cvt_pk_f32_fp8((int)v[j], false);
                v2f h = __builtin_amdgcn_cvt_pk_f32_fp8((int)v[j], true);
                a0 += l.x * w;
                a1 += l.y * w;
                a2 += h.x * w;
                a3 += h.y * w;
            }
        }
        for (; e + 4 <= e1; e += 4) {
            unsigned ed[4]; unsigned v[4];
            #pragma unroll
            for (int j = 0; j < 4; j++) ed[j] = edges[e + j];
            #pragma unroll
            for (int j = 0; j < 4; j++)
                v[j] = base[(size_t)(ed[j] & 0xffffu) * 64 + lane];
            #pragma unroll
            for (int j = 0; j < 4; j++) {
                float w = bfhi(ed[j]);
                v2f l = __builtin_amdgcn_cvt_pk_f32_fp8((int)v[j], false);
                v2f h = __builtin_amdgcn_cvt_pk_f32_fp8((int)v[j], true);
                a0 += l.x * w;
                a1 += l.y * w;
                a2 += h.x * w;
                a3 += h.y * w;
            }
        }
        for (; e < e1; e++) {
            unsigned ed = edges[e];
            float w0 = bfhi(ed);
            unsigned v0 = base[(size_t)(ed & 0xffffu) * 64 + lane];
            v2f l0 = __builtin_amdgcn_cvt_pk_f32_fp8((int)v0, false);
            v2f h0 = __builtin_amdgcn_cvt_pk_f32_fp8((int)v0, true);
            a0 += l0.x * w0;
            a1 += l0.y * w0;
            a2 += h0.x * w0;
            a3 += h0.y * w0;
        }
        uint2 o;
        o.x = (bf16u(a1) << 16) | bf16u(a0);
        o.y = (bf16u(a3) << 16) | bf16u(a2);
        ((uint2*)S)[(size_t)node * 64 + lane] = o;
    }
}

// ----------------- LDS-tiled MFMA bf16 GEMM, 128x256 tile -------------------
// 512 threads = 8 waves (2 row-halves x 4 col-quarters), BK=32.
// Staging via global_load_lds width=16 (3 issues/K-step; wave-linear LDS map).
// OFMT: 0=f32, 1=bf16, 2=fp8 e4m3. POOL=true: segment-pool into g via atomics.
template <int K, int OFMT, bool POOL>
__global__ __launch_bounds__(512) void gemm_tile(
    const ushort* __restrict__ A, const ushort* __restrict__ Wt,
    const float* __restrict__ bias, void* __restrict__ out,
    const int* __restrict__ seg, float* __restrict__ g, int M)
{
    __shared__ __align__(16) ushort As[128 * 32];   // 8 KB
    __shared__ __align__(16) ushort Bs[256 * 32];   // 16 KB
    __shared__ int segsh[128];

    const int tid = threadIdx.x;
    const int bm = blockIdx.x * 128;
    const int wave = tid >> 6, lane = tid & 63;
    const int wm = wave >> 2, wn = wave & 3;
    const int r = lane & 15, q = lane >> 4;

    if (POOL && tid < 128) {
        int gr = bm + tid;
        segsh[tid] = (gr < M) ? seg[gr] : 0x7fffffff;   // sentinel
    }

    const int o0 = tid * 16;           // LDS byte offset, 0..8191 (wave-linear)
    const int row0 = o0 >> 6;          // 0..127
    const int kb0 = o0 & 63;

    const char* Ab = (const char*)A;
    const char* Bb = (const char*)Wt;

    v4f acc[4][4];
    #pragma unroll
    for (int i = 0; i < 4; i++)
        #pragma unroll
        for (int j = 0; j < 4; j++) acc[i][j] = (v4f){0.f, 0.f, 0.f, 0.f};

    const int NK = K / 32;
    for (int ks = 0; ks < NK; ks++) {
        __syncthreads();               // prev MFMA done reading LDS
        gld16(Ab + ((size_t)(bm + row0) * K) * 2 + ks * 64 + kb0,
              (char*)As + o0);
        gld16(Bb + ((size_t)(row0)       * K) * 2 + ks * 64 + kb0,
              (char*)Bs + o0);
        gld16(Bb + ((size_t)(row0 + 128) * K) * 2 + ks * 64 + kb0,
              (char*)Bs + o0 + 8192);
        __syncthreads();               // drains vmcnt(0): LDS-DMA complete

        v8s af[4], bf[4];
        #pragma unroll
        for (int i = 0; i < 4; i++)
            af[i] = *(const v8s*)(As + (wm * 64 + i * 16 + r) * 32 + q * 8);
        #pragma unroll
        for (int j = 0; j < 4; j++)
            bf[j] = *(const v8s*)(Bs + (wn * 64 + j * 16 + r) * 32 + q * 8);
        #pragma unroll
        for (int i = 0; i < 4; i++)
            #pragma unroll
            for (int j = 0; j < 4; j++)
                acc[i][j] = __builtin_amdgcn_mfma_f32_16x16x32_bf16(
                    af[i], bf[j], acc[i][j], 0, 0, 0);
    }

    if constexpr (POOL) {
        #pragma unroll
        for (int j = 0; j < 4; j++) {
            float b = bias[wn * 64 + j * 16 + r];
            #pragma unroll
            for (int i = 0; i < 4; i++)
                #pragma unroll
                for (int ii = 0; ii < 4; ii++)
                    acc[i][j][ii] = fmaxf(acc[i][j][ii] + b, 0.f);
        }
        int myseg[16];
        #pragma unroll
        for (int i = 0; i < 4; i++)
            #pragma unroll
            for (int ii = 0; ii < 4; ii++)
                myseg[i * 4 + ii] = segsh[wm * 64 + i * 16 + q * 4 + ii];
        int s_lo = segsh[0];
        int s_hi = segsh[min(127, M - 1 - bm)];
        for (int s = s_lo; s <= s_hi; s++) {
            #pragma unroll
            for (int j = 0; j < 4; j++) {
                float p = 0.f;
                #pragma unroll
                for (int i = 0; i < 4; i++)
                    #pragma unroll
                    for (int ii = 0; ii < 4; ii++)
                        if (myseg[i * 4 + ii] == s) p += acc[i][j][ii];
                p += __shfl_xor(p, 16, 64);
                p += __shfl_xor(p, 32, 64);
                if (lane < 16)
                    atomicAdd(&g[s * 256 + wn * 64 + j * 16 + r], p);
            }
        }
    } else {
        #pragma unroll
        for (int j = 0; j < 4; j++) {
            int col = wn * 64 + j * 16 + r;
            float b = bias[col];
            #pragma unroll
            for (int i = 0; i < 4; i++) {
                #pragma unroll
                for (int ii = 0; ii < 4; ii++) {
                    int row = bm + wm * 64 + i * 16 + q * 4 + ii;
                    if (row < M) {
                        float v = fmaxf(acc[i][j][ii] + b, 0.f);
                        if constexpr (OFMT == 1) {
                            ((ushort*)out)[(size_t)row * 256 + col] = (ushort)bf16u(v);
                        } else if constexpr (OFMT == 2) {
                            unsigned pk = (unsigned)__builtin_amdgcn_cvt_pk_fp8_f32(
                                v, v, 0, false);
                            ((unsigned char*)out)[(size_t)row * 256 + col] =
                                (unsigned char)(pk & 0xffu);
                        } else {
                            ((float*)out)[(size_t)row * 256 + col] = v;
                        }
                    }
                }
            }
        }
    }
}

// ---------------------------------- head ------------------------------------
__global__ __launch_bounds__(256) void head(
    const float* __restrict__ g, const float* __restrict__ Wd,
    const float* __restrict__ bd, const float* __restrict__ Wo,
    const float* __restrict__ bo, float* __restrict__ out)
{
    __shared__ float gr[256];
    int j = threadIdx.x;
    int gi = blockIdx.x;
    gr[j] = g[(size_t)gi * 256 + j];
    __syncthreads();
    float a2 = bd[j];
    for (int k = 0; k < 256; k++)
        a2 += gr[k] * Wd[(size_t)k * 256 + j];
    a2 = fmaxf(a2, 0.f);

    float v = a2 * Wo[j];
    #pragma unroll
    for (int off = 32; off > 0; off >>= 1)
        v += __shfl_down(v, off, 64);
    __shared__ float partial[4];
    if ((j & 63) == 0) partial[j >> 6] = v;
    __syncthreads();
    if (j == 0)
        out[gi] = partial[0] + partial[1] + partial[2] + partial[3] + bo[0];
}

extern "C" void kernel_launch(void* const* d_in, const int* in_sizes, int n_in,
                              void* d_out, int out_size, void* d_ws, size_t ws_size,
                              hipStream_t stream) {
    const float* x   = (const float*)d_in[0];
    const int*   esrc= (const int*)  d_in[1];
    const int*   edst= (const int*)  d_in[2];
    const float* ew  = (const float*)d_in[3];
    const int*   seg = (const int*)  d_in[4];
    const float* W1  = (const float*)d_in[5];
    const float* b1  = (const float*)d_in[6];
    const float* W2  = (const float*)d_in[7];
    const float* b2  = (const float*)d_in[8];
    const float* Wd  = (const float*)d_in[9];
    const float* bd  = (const float*)d_in[10];
    const float* Wo  = (const float*)d_in[11];
    const float* bo  = (const float*)d_in[12];
    float* out = (float*)d_out;

    const int N = 50000, E = 800000, G = 128, H = 256, F = 128;
    const int NPAD = 50048;            // 391 * 128
    const int NB = (N + 255) / 256;    // 196 (= bucket count)

    // workspace; region0 reused: {x8, S1, stage}; stage dies before spmm128
    char* p = (char*)d_ws;
    char* region0 = p;                  p += (size_t)N * H * sizeof(float);    // 51.2 MB
    unsigned char* x8 = (unsigned char*)region0;                               // [N,128] fp8
    ushort* S1 = (ushort*)(region0 + (size_t)N * F);                           // [NPAD,128] bf16
    uint2* stage = (uint2*)(region0 + (size_t)32 * 1024 * 1024);               // 196*6144*8B = 9.6MB
    unsigned char* h8 = (unsigned char*)p;
                                        p += (size_t)N * H;                    // [N,256] fp8
    ushort* S2 = (ushort*)p;            p += (size_t)NPAD * H * sizeof(ushort);// [NPAD,256] bf16
    float* g   = (float*)p;             p += (size_t)G * H * sizeof(float);
    int*   bcnt= (int*)p;               p += 256 * sizeof(int);                // bucket counts
    int*   off = (int*)p;               p += (size_t)(N + 1) * sizeof(int) + 12;
    unsigned* edges=(unsigned*)p;       p += (size_t)E * sizeof(unsigned);     // packed 4B (src,w)
    ushort* Wt1= (ushort*)p;            p += (size_t)H * F * sizeof(ushort);   // [256,128]
    ushort* Wt2= (ushort*)p;            p += (size_t)H * H * sizeof(ushort);   // [256,256]

    // ---- prep (x->fp8, W^T, bcnt=0) + binned CSR build ----
    prep<<<6763, 256, 0, stream>>>(x, x8, W1, Wt1, W2, Wt2, bcnt);
    bin_pass<<<(E + 2047) / 2048, 256, 0, stream>>>(esrc, edst, ew, bcnt, stage, g, E);
    sort_build<<<NB, 256, 0, stream>>>(stage, bcnt, edges, off, N, E);

    // ---- layer 1: S1 = A@x ; h8 = fp8(relu(S1@W1 + b1)) ----
    spmm128<<<(N + 15) / 16, 256, 0, stream>>>(x8, off, edges, S1, N);
    gemm_tile<128, 2, false><<<NPAD / 128, 512, 0, stream>>>(
        S1, Wt1, b1, h8, nullptr, nullptr, N);

    // ---- layer 2: S2 = A@h8 ; pool(relu(S2@W2+b2)) fused into epilogue ----
    spmm256<<<(N + 15) / 16, 256, 0, stream>>>(h8, off, edges, S2, N);
    gemm_tile<256, 0, true><<<NPAD / 128, 512, 0, stream>>>(
        S2, Wt2, b2, nullptr, seg, g, N);

    // ---- head ----
    head<<<G, 256, 0, stream>>>(g, Wd, bd, Wo, bo, out);
}

// Round 12
// 220.754 us; speedup vs baseline: 1.0234x; 1.0234x over previous
//
#include <hip/hip_runtime.h>
#include <hip/hip_bf16.h>

// ---------------------------------------------------------------------------
// TwoLayerGCN. Round 28: REVERT R27 4-node/wave (225.9 vs 220.8: serializing
// 4 node-chains per wave cut schedulable waves 4x -> lost the TLP that was
// already smoothing Poisson imbalance at CU level; balance lever CLOSED).
// This is R26 exactly (220.8us verified, absmax 0.75, session best).
// Lever ledger (all measured): bytes R17/R20 sub-linear; MLP R21 win / R23
// saturated; XCD-slice R22 falsified; fusion R24 falsified; quant R25 gate
// 0.85 (we're at 0.75); gld16 gemm staging R26 win; balance R27 falsified.
// spmm256 ~33us = HBM random-64B-line floor (~90MB compulsory @ ~2.8TB/s,
// occ 67%, not latency-bound per R23-null) -- structural for this pattern.
// If this round reproduces ~221us with the same counter profile, remaining
// spread is launch-gap + harness poison fill -> roofline next round.
// ---------------------------------------------------------------------------

typedef short v8s __attribute__((ext_vector_type(8)));
typedef float v4f __attribute__((ext_vector_type(4)));
typedef float v2f __attribute__((ext_vector_type(2)));

#define BKT_CAP 6144   // stage capacity per 256-node bucket (mean 4096, std 64)

__device__ inline unsigned bf16u(float f) {           // fp32 -> bf16 bits (RNE)
    unsigned u = __builtin_bit_cast(unsigned, f);
    return (u + 0x7fffu + ((u >> 16) & 1u)) >> 16;
}
__device__ inline float bflo(unsigned v) { return __builtin_bit_cast(float, v << 16); }
__device__ inline float bfhi(unsigned v) { return __builtin_bit_cast(float, v & 0xffff0000u); }

__device__ __forceinline__ void gld16(const void* gsrc, void* ldst) {
    __builtin_amdgcn_global_load_lds(
        (const __attribute__((address_space(1))) void*)gsrc,
        (__attribute__((address_space(3))) void*)ldst, 16, 0, 0);
}

// ------------- fused prep: x->fp8, W^T, bcnt zero (no memset) ---------------
__global__ __launch_bounds__(256) void prep(
    const float* __restrict__ x, unsigned char* __restrict__ x8,
    const float* __restrict__ W1, ushort* __restrict__ Wt1,
    const float* __restrict__ W2, ushort* __restrict__ Wt2,
    int* __restrict__ bcnt)
{
    int b = blockIdx.x;
    int t = threadIdx.x;
    if (b < 6250) {
        int i = b * 256 + t;                 // n4 = 1600000
        if (i < 1600000) {
            float4 v = ((const float4*)x)[i];
            int pk = __builtin_amdgcn_cvt_pk_fp8_f32(v.x, v.y, 0, false);
            pk = __builtin_amdgcn_cvt_pk_fp8_f32(v.z, v.w, pk, true);
            ((unsigned*)x8)[i] = (unsigned)pk;
        }
    } else if (b < 6506) {
        int n = b - 6250;
        if (t < 128) Wt1[n * 128 + t] = (ushort)bf16u(W1[t * 256 + n]);
    } else if (b < 6762) {
        int n = b - 6506;
        Wt2[n * 256 + t] = (ushort)bf16u(W2[t * 256 + n]);
    } else {
        bcnt[t] = 0;
    }
}

// --------------- pass A: bin edges by 256-node bucket (dst>>8) --------------
__global__ __launch_bounds__(256) void bin_pass(
    const int* __restrict__ src, const int* __restrict__ dst,
    const float* __restrict__ w, int* __restrict__ bcnt,
    uint2* __restrict__ stage, float* __restrict__ g, int E)
{
    __shared__ int hist[256];
    __shared__ int excl[256];
    __shared__ int gbase[256];
    __shared__ uint2 stg[2048];

    int t = threadIdx.x, b = blockIdx.x;
    if (b < 128) g[b * 256 + t] = 0.f;

    int e0 = b * 2048;
    hist[t] = 0;
    __syncthreads();

    int d_[8]; unsigned pk_[8]; int rk_[8]; int bk_[8];
    #pragma unroll
    for (int j = 0; j < 8; j++) {
        int e = e0 + t + j * 256;               // coalesced
        if (e < E) {
            int d = dst[e];
            d_[j] = d;
            bk_[j] = d >> 8;
            pk_[j] = (unsigned)src[e] | (bf16u(w[e]) << 16);
            rk_[j] = atomicAdd(&hist[bk_[j]], 1);
        } else d_[j] = -1;
    }
    __syncthreads();

    int cnt = hist[t];
    excl[t] = cnt;
    __syncthreads();
    for (int o = 1; o < 256; o <<= 1) {         // inclusive scan
        int v = (t >= o) ? excl[t - o] : 0;
        __syncthreads();
        excl[t] += v;
        __syncthreads();
    }
    int ex = excl[t] - cnt;                     // exclusive
    if (cnt > 0) gbase[t] = atomicAdd(&bcnt[t], cnt);   // reserve run
    __syncthreads();
    excl[t] = ex;
    __syncthreads();

    #pragma unroll
    for (int j = 0; j < 8; j++)
        if (d_[j] >= 0)
            stg[excl[bk_[j]] + rk_[j]] = make_uint2(pk_[j], (unsigned)d_[j]);
    __syncthreads();

    int nval = min(2048, E - e0);
    #pragma unroll
    for (int j = 0; j < 8; j++) {
        int sidx = t + j * 256;                 // consecutive lanes -> consecutive gpos
        if (sidx < nval) {
            uint2 ent = stg[sidx];
            int bk = (int)(ent.y >> 8);
            stage[(size_t)bk * BKT_CAP + gbase[bk] + sidx - excl[bk]] = ent;
        }
    }
}

// ------ pass B: per-bucket histogram + scan -> off[], sort -> edges[] -------
__global__ __launch_bounds__(256) void sort_build(
    const uint2* __restrict__ stage, const int* __restrict__ bcnt,
    unsigned* __restrict__ edges, int* __restrict__ off, int N, int E)
{
    __shared__ unsigned sorted[BKT_CAP];        // 24 KB
    __shared__ int hist[256];
    __shared__ int s[256];
    __shared__ int cur[256];
    __shared__ int psum[4];
    __shared__ int sbase;

    int t = threadIdx.x, b = blockIdx.x;
    const uint2* reg = stage + (size_t)b * BKT_CAP;
    int cnt = bcnt[b];

    // bucket base = sum of bcnt[0..b-1]
    int pred = (t < b) ? bcnt[t] : 0;
    #pragma unroll
    for (int o = 32; o > 0; o >>= 1) pred += __shfl_down(pred, o, 64);
    if ((t & 63) == 0) psum[t >> 6] = pred;
    hist[t] = 0;
    __syncthreads();
    if (t == 0) sbase = psum[0] + psum[1] + psum[2] + psum[3];

    for (int i = t; i < cnt; i += 256)
        atomicAdd(&hist[reg[i].y & 255u], 1);   // LDS atomic
    __syncthreads();

    int h = hist[t];
    s[t] = h;
    __syncthreads();
    for (int o = 1; o < 256; o <<= 1) {         // inclusive scan
        int v = (t >= o) ? s[t - o] : 0;
        __syncthreads();
        s[t] += v;
        __syncthreads();
    }
    int ex = s[t] - h;                          // exclusive
    cur[t] = ex;
    __syncthreads();

    int nn = b * 256 + t;
    if (nn <= N) off[nn] = sbase + ex;          // nn==N lands off[N]=E exactly

    for (int i = t; i < cnt; i += 256) {
        uint2 ent = reg[i];
        int r = atomicAdd(&cur[ent.y & 255u], 1);
        sorted[r] = ent.x;
    }
    __syncthreads();
    for (int i = t; i < cnt; i += 256)
        edges[sbase + i] = sorted[i];
}

// --------------- gather SpMM layer 1: fp8 e4m3 in, bf16 out -----------------
// 16-deep gather pipeline (R21/R23, verified).
__global__ __launch_bounds__(256) void spmm128(
    const unsigned char* __restrict__ x8, const int* __restrict__ off,
    const unsigned* __restrict__ edges, ushort* __restrict__ S, int n)
{
    int node = blockIdx.x * 4 + (threadIdx.x >> 6);
    if (node >= n) return;
    int lane = threadIdx.x & 63;
    const ushort* base = (const ushort*)x8;   // row stride 64 ushorts (128B)
    int e0 = off[node], e1 = off[node + 1];
    float a0 = 0.f, a1 = 0.f;
    int e = e0;
    for (; e + 16 <= e1; e += 16) {
        unsigned ed[16]; ushort v[16];
        #pragma unroll
        for (int j = 0; j < 16; j++) ed[j] = edges[e + j];
        #pragma unroll
        for (int j = 0; j < 16; j++)
            v[j] = base[(size_t)(ed[j] & 0xffffu) * 64 + lane];
        #pragma unroll
        for (int j = 0; j < 16; j++) {
            float w = bfhi(ed[j]);
            v2f f = __builtin_amdgcn_cvt_pk_f32_fp8((int)v[j], false);
            a0 += f.x * w;
            a1 += f.y * w;
        }
    }
    for (; e + 4 <= e1; e += 4) {
        unsigned ed[4]; ushort v[4];
        #pragma unroll
        for (int j = 0; j < 4; j++) ed[j] = edges[e + j];
        #pragma unroll
        for (int j = 0; j < 4; j++)
            v[j] = base[(size_t)(ed[j] & 0xffffu) * 64 + lane];
        #pragma unroll
        for (int j = 0; j < 4; j++) {
            float w = bfhi(ed[j]);
            v2f f = __builtin_amdgcn_cvt_pk_f32_fp8((int)v[j], false);
            a0 += f.x * w;
            a1 += f.y * w;
        }
    }
    for (; e < e1; e++) {
        unsigned ed = edges[e];
        float w0 = bfhi(ed);
        ushort v0 = base[(size_t)(ed & 0xffffu) * 64 + lane];
        v2f f0 = __builtin_amdgcn_cvt_pk_f32_fp8((int)v0, false);
        a0 += f0.x * w0;
        a1 += f0.y * w0;
    }
    ((unsigned*)S)[(size_t)node * 64 + lane] = (bf16u(a1) << 16) | bf16u(a0);
}

// --------------- gather SpMM layer 2: fp8 e4m3 in, bf16 out -----------------
// 16-deep gather pipeline (R21/R23, verified).
__global__ __launch_bounds__(256) void spmm256(
    const unsigned char* __restrict__ h8, const int* __restrict__ off,
    const unsigned* __restrict__ edges, ushort* __restrict__ S, int n)
{
    int node = blockIdx.x * 4 + (threadIdx.x >> 6);
    if (node >= n) return;
    int lane = threadIdx.x & 63;
    const unsigned* base = (const unsigned*)h8;    // row stride 64 uints (256B)
    int e0 = off[node], e1 = off[node + 1];
    float a0 = 0.f, a1 = 0.f, a2 = 0.f, a3 = 0.f;
    int e = e0;
    for (; e + 16 <= e1; e += 16) {
        unsigned ed[16]; unsigned v[16];
        #pragma unroll
        for (int j = 0; j < 16; j++) ed[j] = edges[e + j];
        #pragma unroll
        for (int j = 0; j < 16; j++)
            v[j] = base[(size_t)(ed[j] & 0xffffu) * 64 + lane];
        #pragma unroll
        for (int j = 0; j < 16; j++) {
            float w = bfhi(ed[j]);
            v2f l = __builtin_amdgcn_cvt_pk_f32_fp8((int)v[j], false);
            v2f h = __builtin_amdgcn_cvt_pk_f32_fp8((int)v[j], true);
            a0 += l.x * w;
            a1 += l.y * w;
            a2 += h.x * w;
            a3 += h.y * w;
        }
    }
    for (; e + 4 <= e1; e += 4) {
        unsigned ed[4]; unsigned v[4];
        #pragma unroll
        for (int j = 0; j < 4; j++) ed[j] = edges[e + j];
        #pragma unroll
        for (int j = 0; j < 4; j++)
            v[j] = base[(size_t)(ed[j] & 0xffffu) * 64 + lane];
        #pragma unroll
        for (int j = 0; j < 4; j++) {
            float w = bfhi(ed[j]);
            v2f l = __builtin_amdgcn_cvt_pk_f32_fp8((int)v[j], false);
            v2f h = __builtin_amdgcn_cvt_pk_f32_fp8((int)v[j], true);
            a0 += l.x * w;
            a1 += l.y * w;
            a2 += h.x * w;
            a3 += h.y * w;
        }
    }
    for (; e < e1; e++) {
        unsigned ed = edges[e];
        float w0 = bfhi(ed);
        unsigned v0 = base[(size_t)(ed & 0xffffu) * 64 + lane];
        v2f l0 = __builtin_amdgcn_cvt_pk_f32_fp8((int)v0, false);
        v2f h0 = __builtin_amdgcn_cvt_pk_f32_fp8((int)v0, true);
        a0 += l0.x * w0;
        a1 += l0.y * w0;
        a2 += h0.x * w0;
        a3 += h0.y * w0;
    }
    uint2 o;
    o.x = (bf16u(a1) << 16) | bf16u(a0);
    o.y = (bf16u(a3) << 16) | bf16u(a2);
    ((uint2*)S)[(size_t)node * 64 + lane] = o;
}

// ----------------- LDS-tiled MFMA bf16 GEMM, 128x256 tile -------------------
// 512 threads = 8 waves (2 row-halves x 4 col-quarters), BK=32.
// Staging via global_load_lds width=16 (3 issues/K-step; wave-linear LDS map).
// OFMT: 0=f32, 1=bf16, 2=fp8 e4m3. POOL=true: segment-pool into g via atomics.
template <int K, int OFMT, bool POOL>
__global__ __launch_bounds__(512) void gemm_tile(
    const ushort* __restrict__ A, const ushort* __restrict__ Wt,
    const float* __restrict__ bias, void* __restrict__ out,
    const int* __restrict__ seg, float* __restrict__ g, int M)
{
    __shared__ __align__(16) ushort As[128 * 32];   // 8 KB
    __shared__ __align__(16) ushort Bs[256 * 32];   // 16 KB
    __shared__ int segsh[128];

    const int tid = threadIdx.x;
    const int bm = blockIdx.x * 128;
    const int wave = tid >> 6, lane = tid & 63;
    const int wm = wave >> 2, wn = wave & 3;
    const int r = lane & 15, q = lane >> 4;

    if (POOL && tid < 128) {
        int gr = bm + tid;
        segsh[tid] = (gr < M) ? seg[gr] : 0x7fffffff;   // sentinel
    }

    const int o0 = tid * 16;           // LDS byte offset, 0..8191 (wave-linear)
    const int row0 = o0 >> 6;          // 0..127
    const int kb0 = o0 & 63;

    const char* Ab = (const char*)A;
    const char* Bb = (const char*)Wt;

    v4f acc[4][4];
    #pragma unroll
    for (int i = 0; i < 4; i++)
        #pragma unroll
        for (int j = 0; j < 4; j++) acc[i][j] = (v4f){0.f, 0.f, 0.f, 0.f};

    const int NK = K / 32;
    for (int ks = 0; ks < NK; ks++) {
        __syncthreads();               // prev MFMA done reading LDS
        gld16(Ab + ((size_t)(bm + row0) * K) * 2 + ks * 64 + kb0,
              (char*)As + o0);
        gld16(Bb + ((size_t)(row0)       * K) * 2 + ks * 64 + kb0,
              (char*)Bs + o0);
        gld16(Bb + ((size_t)(row0 + 128) * K) * 2 + ks * 64 + kb0,
              (char*)Bs + o0 + 8192);
        __syncthreads();               // drains vmcnt(0): LDS-DMA complete

        v8s af[4], bf[4];
        #pragma unroll
        for (int i = 0; i < 4; i++)
            af[i] = *(const v8s*)(As + (wm * 64 + i * 16 + r) * 32 + q * 8);
        #pragma unroll
        for (int j = 0; j < 4; j++)
            bf[j] = *(const v8s*)(Bs + (wn * 64 + j * 16 + r) * 32 + q * 8);
        #pragma unroll
        for (int i = 0; i < 4; i++)
            #pragma unroll
            for (int j = 0; j < 4; j++)
                acc[i][j] = __builtin_amdgcn_mfma_f32_16x16x32_bf16(
                    af[i], bf[j], acc[i][j], 0, 0, 0);
    }

    if constexpr (POOL) {
        #pragma unroll
        for (int j = 0; j < 4; j++) {
            float b = bias[wn * 64 + j * 16 + r];
            #pragma unroll
            for (int i = 0; i < 4; i++)
                #pragma unroll
                for (int ii = 0; ii < 4; ii++)
                    acc[i][j][ii] = fmaxf(acc[i][j][ii] + b, 0.f);
        }
        int myseg[16];
        #pragma unroll
        for (int i = 0; i < 4; i++)
            #pragma unroll
            for (int ii = 0; ii < 4; ii++)
                myseg[i * 4 + ii] = segsh[wm * 64 + i * 16 + q * 4 + ii];
        int s_lo = segsh[0];
        int s_hi = segsh[min(127, M - 1 - bm)];
        for (int s = s_lo; s <= s_hi; s++) {
            #pragma unroll
            for (int j = 0; j < 4; j++) {
                float p = 0.f;
                #pragma unroll
                for (int i = 0; i < 4; i++)
                    #pragma unroll
                    for (int ii = 0; ii < 4; ii++)
                        if (myseg[i * 4 + ii] == s) p += acc[i][j][ii];
                p += __shfl_xor(p, 16, 64);
                p += __shfl_xor(p, 32, 64);
                if (lane < 16)
                    atomicAdd(&g[s * 256 + wn * 64 + j * 16 + r], p);
            }
        }
    } else {
        #pragma unroll
        for (int j = 0; j < 4; j++) {
            int col = wn * 64 + j * 16 + r;
            float b = bias[col];
            #pragma unroll
            for (int i = 0; i < 4; i++) {
                #pragma unroll
                for (int ii = 0; ii < 4; ii++) {
                    int row = bm + wm * 64 + i * 16 + q * 4 + ii;
                    if (row < M) {
                        float v = fmaxf(acc[i][j][ii] + b, 0.f);
                        if constexpr (OFMT == 1) {
                            ((ushort*)out)[(size_t)row * 256 + col] = (ushort)bf16u(v);
                        } else if constexpr (OFMT == 2) {
                            unsigned pk = (unsigned)__builtin_amdgcn_cvt_pk_fp8_f32(
                                v, v, 0, false);
                            ((unsigned char*)out)[(size_t)row * 256 + col] =
                                (unsigned char)(pk & 0xffu);
                        } else {
                            ((float*)out)[(size_t)row * 256 + col] = v;
                        }
                    }
                }
            }
        }
    }
}

// ---------------------------------- head ------------------------------------
__global__ __launch_bounds__(256) void head(
    const float* __restrict__ g, const float* __restrict__ Wd,
    const float* __restrict__ bd, const float* __restrict__ Wo,
    const float* __restrict__ bo, float* __restrict__ out)
{
    __shared__ float gr[256];
    int j = threadIdx.x;
    int gi = blockIdx.x;
    gr[j] = g[(size_t)gi * 256 + j];
    __syncthreads();
    float a2 = bd[j];
    for (int k = 0; k < 256; k++)
        a2 += gr[k] * Wd[(size_t)k * 256 + j];
    a2 = fmaxf(a2, 0.f);

    float v = a2 * Wo[j];
    #pragma unroll
    for (int off = 32; off > 0; off >>= 1)
        v += __shfl_down(v, off, 64);
    __shared__ float partial[4];
    if ((j & 63) == 0) partial[j >> 6] = v;
    __syncthreads();
    if (j == 0)
        out[gi] = partial[0] + partial[1] + partial[2] + partial[3] + bo[0];
}

extern "C" void kernel_launch(void* const* d_in, const int* in_sizes, int n_in,
                              void* d_out, int out_size, void* d_ws, size_t ws_size,
                              hipStream_t stream) {
    const float* x   = (const float*)d_in[0];
    const int*   esrc= (const int*)  d_in[1];
    const int*   edst= (const int*)  d_in[2];
    const float* ew  = (const float*)d_in[3];
    const int*   seg = (const int*)  d_in[4];
    const float* W1  = (const float*)d_in[5];
    const float* b1  = (const float*)d_in[6];
    const float* W2  = (const float*)d_in[7];
    const float* b2  = (const float*)d_in[8];
    const float* Wd  = (const float*)d_in[9];
    const float* bd  = (const float*)d_in[10];
    const float* Wo  = (const float*)d_in[11];
    const float* bo  = (const float*)d_in[12];
    float* out = (float*)d_out;

    const int N = 50000, E = 800000, G = 128, H = 256, F = 128;
    const int NPAD = 50048;            // 391 * 128
    const int NB = (N + 255) / 256;    // 196 (= bucket count)

    // workspace; region0 reused: {x8, S1, stage}; stage dies before spmm128
    char* p = (char*)d_ws;
    char* region0 = p;                  p += (size_t)N * H * sizeof(float);    // 51.2 MB
    unsigned char* x8 = (unsigned char*)region0;                               // [N,128] fp8
    ushort* S1 = (ushort*)(region0 + (size_t)N * F);                           // [NPAD,128] bf16
    uint2* stage = (uint2*)(region0 + (size_t)32 * 1024 * 1024);               // 196*6144*8B = 9.6MB
    unsigned char* h8 = (unsigned char*)p;
                                        p += (size_t)N * H;                    // [N,256] fp8
    ushort* S2 = (ushort*)p;            p += (size_t)NPAD * H * sizeof(ushort);// [NPAD,256] bf16
    float* g   = (float*)p;             p += (size_t)G * H * sizeof(float);
    int*   bcnt= (int*)p;               p += 256 * sizeof(int);                // bucket counts
    int*   off = (int*)p;               p += (size_t)(N + 1) * sizeof(int) + 12;
    unsigned* edges=(unsigned*)p;       p += (size_t)E * sizeof(unsigned);     // packed 4B (src,w)
    ushort* Wt1= (ushort*)p;            p += (size_t)H * F * sizeof(ushort);   // [256,128]
    ushort* Wt2= (ushort*)p;            p += (size_t)H * H * sizeof(ushort);   // [256,256]

    // ---- prep (x->fp8, W^T, bcnt=0) + binned CSR build ----
    prep<<<6763, 256, 0, stream>>>(x, x8, W1, Wt1, W2, Wt2, bcnt);
    bin_pass<<<(E + 2047) / 2048, 256, 0, stream>>>(esrc, edst, ew, bcnt, stage, g, E);
    sort_build<<<NB, 256, 0, stream>>>(stage, bcnt, edges, off, N, E);

    // ---- layer 1: S1 = A@x ; h8 = fp8(relu(S1@W1 + b1)) ----
    spmm128<<<(N + 3) / 4, 256, 0, stream>>>(x8, off, edges, S1, N);
    gemm_tile<128, 2, false><<<NPAD / 128, 512, 0, stream>>>(
        S1, Wt1, b1, h8, nullptr, nullptr, N);

    // ---- layer 2: S2 = A@h8 ; pool(relu(S2@W2+b2)) fused into epilogue ----
    spmm256<<<(N + 3) / 4, 256, 0, stream>>>(h8, off, edges, S2, N);
    gemm_tile<256, 0, true><<<NPAD / 128, 512, 0, stream>>>(
        S2, Wt2, b2, nullptr, seg, g, N);

    // ---- head ----
    head<<<G, 256, 0, stream>>>(g, Wd, bd, Wo, bo, out);
}